// Round 11
// baseline (142.932 us; speedup 1.0000x reference)
//
#include <hip/hip_runtime.h>
#include <hip/hip_bf16.h>

// Problem constants
#define B_  128
#define I_  64
#define P_  16
#define T_  5
#define NT  3
#define VOCAB 100000
#define D_  64
#define NPAIR (B_ * I_)        // 8192 (n)
#define OUTROWS NPAIR          // 8192 output rows of 64

// ---------- bf16 helpers ----------
__device__ __forceinline__ unsigned short f2b(float f) {
    unsigned int u = __float_as_uint(f);
    return (unsigned short)((u + 0x7fffu + ((u >> 16) & 1u)) >> 16);   // RNE
}

typedef short short8 __attribute__((ext_vector_type(8)));
typedef float f32x4 __attribute__((ext_vector_type(4)));

#define AROW_STRIDE 160                  // LDS row stride in bytes
#define AWAVE_BYTES (40 * AROW_STRIDE)   // 6400 per wave (40 rows)

// =====================================================================
// wprep: bf16 weight fragments in EXACT mfma first-operand lane order.
// Entry e = ((cb*2+half)*4+quad)*16 + m holds 8 shorts (16B):
//   channel c = cb*16+m, k = half*32 + quad*8 + j
// =====================================================================
__global__ __launch_bounds__(256) void wprep(
        const float* __restrict__ convw, unsigned short* __restrict__ Wf) {
    const int e0 = threadIdx.x * 4;
#pragma unroll
    for (int e = e0; e < e0 + 4; ++e) {
        int m = e & 15;
        int quad = (e >> 4) & 3;
        int half = (e >> 6) & 1;
        int cb = e >> 7;
        int c = cb * 16 + m;
        const float* wp = (c < 64) ? (convw + c * 128) : (convw + (c - 64) * 128 + 1);
#pragma unroll
        for (int j = 0; j < 8; ++j) {
            int k = half * 32 + quad * 8 + j;
            Wf[e * 8 + j] = f2b(wp[k * 2]);
        }
    }
}

// =====================================================================
// FUSED kernel, split-wave edition: block = 4 waves = 2 nn; each nn's
// 16 pp split across 2 waves (ph=0: pp 0-7, ph=1: pp 8-15).
// - dense gathers: instr i reads 4 full rows contiguously (segment-
//   optimal 2x128B per row), 10 instr/wave
// - per-wave LDS staging (40 rows x 160B = 6.4KB; block 26.6KB -> up
//   to 6 blocks/CU vs R9's 3) -> ~1.5-2x resident waves for MLP
// - compute lanes l16>=8 duplicate rows 0-7 (l16&7): shfl-max over 16
//   columns is then max over the 8 real pp
// - cross-wave (ph) merge via part[] LDS + one barrier (R5 pattern)
// =====================================================================
__global__ __launch_bounds__(256) void fused_path(
        const int* __restrict__ path_input, const int* __restrict__ path_type,
        const float* __restrict__ tables, const unsigned short* __restrict__ Wf,
        const float* __restrict__ bias, float* __restrict__ out) {
    __shared__ __align__(16) unsigned char Asmem[4][AWAVE_BYTES];   // 25600 B
    __shared__ float part[2][2][64];                                 // 1024 B
    const int tid = threadIdx.x;
    const int w = tid >> 6;
    const int lane = tid & 63;
    const int l16 = lane & 15;      // pp_local (compute) / c16 (gather)
    const int quad = lane >> 4;
    const int r2 = lane >> 4;       // row-within-group (gather): 0..3
    const int c16 = lane & 15;      // 16B chunk within row (gather)

    const int ln = w & 1;           // which nn in block
    const int ph = w >> 1;          // pp half: 0 -> pp 0..7, 1 -> pp 8..15
    const int nn = blockIdx.x * 2 + ln;
    const int g = nn >> 4, q = nn & 15;
    unsigned char* myA = Asmem[w];

    // ---- weight fragments (16KB buffer, L1/L2-resident) ----
    short8 WB0[8], WB1[8];
#pragma unroll
    for (int ns = 0; ns < 8; ++ns) {
        WB0[ns] = *(const short8*)&Wf[((ns * 8 + 0 + quad) * 16 + l16) * 8];
        WB1[ns] = *(const short8*)&Wf[((ns * 8 + 4 + quad) * 16 + l16) * 8];
    }

    // ---- row indices: 10 broadcast loads (16 lanes share each addr) ----
    int roff[10];   // rowid * 64
#pragma unroll
    for (int i = 0; i < 10; ++i) {
        int t = i >> 1, sub = i & 1;
        int ppl = sub * 4 + r2;               // pp_local 0..7
        int pp = ph * 8 + ppl;
        int addr = ((pp * 512 + g) * 16 + q) * 5 + t;
        roff[i] = (path_type[t] * VOCAB + path_input[addr]) * 64;
    }

    // ---- dense gathers: 16B contiguous per lane, 4 full rows per instr ----
    float4 F[10];
#pragma unroll
    for (int i = 0; i < 10; ++i)
        F[i] = *(const float4*)(tables + (size_t)roff[i] + c16 * 4);

    // ---- convert + stage to LDS (bf16, per-wave region, no barrier) ----
#pragma unroll
    for (int i = 0; i < 10; ++i) {
        int t = i >> 1, sub = i & 1;
        int R = t * 8 + sub * 4 + r2;         // 0..39
        unsigned int p0 = (unsigned int)f2b(F[i].x) | ((unsigned int)f2b(F[i].y) << 16);
        unsigned int p1 = (unsigned int)f2b(F[i].z) | ((unsigned int)f2b(F[i].w) << 16);
        uint2 pk; pk.x = p0; pk.y = p1;
        *(uint2*)(myA + R * AROW_STRIDE + c16 * 8) = pk;
    }

    // ---- read MFMA A-fragments; lanes l16>=8 duplicate rows (l16&7) ----
    short8 A0[5], A1[5];
#pragma unroll
    for (int t = 0; t < 5; ++t) {
        const unsigned char* rp = myA + (t * 8 + (l16 & 7)) * AROW_STRIDE;
        A0[t] = *(const short8*)(rp + quad * 16);          // bf16 k 0..31
        A1[t] = *(const short8*)(rp + 64 + quad * 16);     // bf16 k 32..63
    }

    // ---- windows: runmax over to of U_to + V_{to+1} ----
    f32x4 runmax[4];
#pragma unroll
    for (int ns = 0; ns < 4; ++ns) runmax[ns] = (f32x4){-1e30f, -1e30f, -1e30f, -1e30f};
#pragma unroll
    for (int to = 0; to < 4; ++to) {
#pragma unroll
        for (int ns = 0; ns < 4; ++ns) {
            f32x4 uu = {0.f, 0.f, 0.f, 0.f};
            uu = __builtin_amdgcn_mfma_f32_16x16x32_bf16(WB0[ns], A0[to], uu, 0, 0, 0);
            uu = __builtin_amdgcn_mfma_f32_16x16x32_bf16(WB1[ns], A1[to], uu, 0, 0, 0);
            f32x4 vv = {0.f, 0.f, 0.f, 0.f};
            vv = __builtin_amdgcn_mfma_f32_16x16x32_bf16(WB0[ns + 4], A0[to + 1], vv, 0, 0, 0);
            vv = __builtin_amdgcn_mfma_f32_16x16x32_bf16(WB1[ns + 4], A1[to + 1], vv, 0, 0, 0);
#pragma unroll
            for (int j = 0; j < 4; ++j)
                runmax[ns][j] = fmaxf(runmax[ns][j], uu[j] + vv[j]);
        }
    }

    // ---- max over the 16 D-columns (8 real pp + 8 duplicates) ----
#pragma unroll
    for (int ns = 0; ns < 4; ++ns) {
#pragma unroll
        for (int j = 0; j < 4; ++j) {
            float v = runmax[ns][j];
            v = fmaxf(v, __shfl_xor(v, 1));
            v = fmaxf(v, __shfl_xor(v, 2));
            v = fmaxf(v, __shfl_xor(v, 4));
            v = fmaxf(v, __shfl_xor(v, 8));
            runmax[ns][j] = v;
        }
    }
    if (l16 == 0) {
        // lane (0, quad) holds channels ns*16 + quad*4 + j
#pragma unroll
        for (int ns = 0; ns < 4; ++ns) {
#pragma unroll
            for (int j = 0; j < 4; ++j)
                part[ln][ph][ns * 16 + quad * 4 + j] = runmax[ns][j];
        }
    }
    __syncthreads();
    if (tid < 128) {
        int oln = tid >> 6, c = tid & 63;
        float v = fmaxf(part[oln][0][c], part[oln][1][c]) + bias[c];
        out[(size_t)(blockIdx.x * 2 + oln) * 64 + c] = v;
    }
}

// =====================================================================
// Fallback (if workspace too small): direct fused fp32.
// =====================================================================
__global__ __launch_bounds__(64) void fused_direct(
        const int* __restrict__ path_input, const int* __restrict__ path_type,
        const float* __restrict__ tables, const float* __restrict__ convw,
        const float* __restrict__ bias, float* __restrict__ out) {
    const int nn = blockIdx.x;
    const int o = threadIdx.x;
    const int g = nn >> 4;
    const int q = nn & 15;
    float w0[64], w1[64];
#pragma unroll
    for (int i = 0; i < 64; ++i) {
        w0[i] = convw[o * 128 + i * 2];
        w1[i] = convw[o * 128 + i * 2 + 1];
    }
    int tb[5];
#pragma unroll
    for (int t = 0; t < 5; ++t) tb[t] = path_type[t] * VOCAB;
    __shared__ float emb[5][64];
    float acc = -1e30f;
    for (int pp = 0; pp < 16; ++pp) {
        int m = pp * 512 + g;
        const int* ip = path_input + ((m * 16 + q) * 5);
        __syncthreads();
#pragma unroll
        for (int t = 0; t < 5; ++t)
            emb[t][o] = tables[(size_t)(tb[t] + ip[t]) * 64 + o];
        __syncthreads();
#pragma unroll
        for (int to = 0; to < 4; ++to) {
            float s = 0.f;
#pragma unroll
            for (int i = 0; i < 64; ++i)
                s += w0[i] * emb[to][i] + w1[i] * emb[to + 1][i];
            acc = fmaxf(acc, s);
        }
    }
    out[(size_t)nn * 64 + o] = acc + bias[o];
}

extern "C" void kernel_launch(void* const* d_in, const int* in_sizes, int n_in,
                              void* d_out, int out_size, void* d_ws, size_t ws_size,
                              hipStream_t stream) {
    const int*   path_input = (const int*)d_in[0];
    const int*   path_type  = (const int*)d_in[1];
    const float* tables     = (const float*)d_in[2];
    const float* convw      = (const float*)d_in[3];
    const float* convb      = (const float*)d_in[4];
    float* out = (float*)d_out;

    const size_t needWf = (size_t)16 * 1024 * sizeof(unsigned short);   // 32 KB
    if (ws_size >= needWf) {
        unsigned short* Wf = (unsigned short*)d_ws;
        wprep<<<1, 256, 0, stream>>>(convw, Wf);
        fused_path<<<OUTROWS / 2, 256, 0, stream>>>(path_input, path_type,
                                                    tables, Wf, convb, out);
    } else {
        fused_direct<<<OUTROWS, 64, 0, stream>>>(path_input, path_type, tables, convw, convb, out);
    }
}